// Round 11
// baseline (146.805 us; speedup 1.0000x reference)
//
#include <hip/hip_runtime.h>
#include <stdint.h>

#define B 8
#define N 460800
#define NV4 115200          // N/4 float4 scores per image
#define PRE 2000
#define POST 1000
#define CAP 4096
#define NBIN 4096
#define RANKP 2048
#define NWORD 32
#define NMS_T 0.7f
#define XCLIP 4.135166556742356

#define SCAN_BLOCKS 45      // 45*256*10 = 115200
#define SCAN_ITER 10
#define SCAN_STRIDE (SCAN_BLOCKS * 256)

typedef unsigned long long u64;

__device__ __forceinline__ uint32_t fkey(float f) {
    uint32_t u = __float_as_uint(f);
    return (u & 0x80000000u) ? ~u : (u | 0x80000000u);
}

__device__ __forceinline__ u64 readlane_u64(u64 v, int lane) {
    uint32_t lo = __builtin_amdgcn_readlane((uint32_t)v, lane);
    uint32_t hi = __builtin_amdgcn_readlane((uint32_t)(v >> 32), lane);
    return ((u64)hi << 32) | lo;
}

// async global->LDS DMA, 16B per lane: dest = lds_base (uniform) + lane*16.
__device__ __forceinline__ void gload_lds16(const void* g, void* l) {
    __builtin_amdgcn_global_load_lds(
        (const __attribute__((address_space(1))) void*)g,
        (__attribute__((address_space(3))) void*)l, 16, 0, 0);
}

// LDS byte offset of a __shared__ pointer (AS3 ptrs are 32-bit offsets).
__device__ __forceinline__ uint32_t lds_addr(const void* p) {
    return (uint32_t)(uintptr_t)(const __attribute__((address_space(3))) void*)p;
}

// ---------------- Stage 1: per-image histogram of score keys (top 12 bits) ----------------
__global__ __launch_bounds__(256) void k_hist(const float4* __restrict__ obj4,
                                              uint32_t* __restrict__ hist) {
    __shared__ uint32_t lh[2][NBIN];   // 32 KiB, 2-way replicated to cut contention
    int b = blockIdx.y;
    for (int i = threadIdx.x; i < NBIN; i += 256) { lh[0][i] = 0; lh[1][i] = 0; }
    __syncthreads();
    const float4* s = obj4 + (size_t)b * NV4;
    int t0 = blockIdx.x * 256 + threadIdx.x;
    uint32_t* h = lh[threadIdx.x & 1];
    float4 v[SCAN_ITER];
#pragma unroll
    for (int k = 0; k < SCAN_ITER; ++k) v[k] = s[t0 + k * SCAN_STRIDE];
#pragma unroll
    for (int k = 0; k < SCAN_ITER; ++k) {
        atomicAdd(&h[fkey(v[k].x) >> 20], 1u);
        atomicAdd(&h[fkey(v[k].y) >> 20], 1u);
        atomicAdd(&h[fkey(v[k].z) >> 20], 1u);
        atomicAdd(&h[fkey(v[k].w) >> 20], 1u);
    }
    __syncthreads();
    uint32_t* gh = hist + (size_t)b * NBIN;
    for (int i = threadIdx.x; i < NBIN; i += 256) {
        uint32_t s2 = lh[0][i] + lh[1][i];
        if (s2) atomicAdd(&gh[i], s2);
    }
}

// ---------------- Stage 2+3 fused: wave 0 computes cutoff bin, then compact ------------
#define LBUF 2048
__global__ __launch_bounds__(256) void k_compact(const float4* __restrict__ obj4,
                                                 const uint32_t* __restrict__ hist,
                                                 uint32_t* __restrict__ cnt,
                                                 u64* __restrict__ cand) {
    __shared__ u64 buf[LBUF];          // 16 KiB
    __shared__ uint32_t lcnt, base, cutsh;
    int b = blockIdx.y;
    if (threadIdx.x == 0) lcnt = 0;
    if (threadIdx.x < 64) {
        int lane = threadIdx.x;
        const uint32_t* h = hist + (size_t)b * NBIN;
        uint32_t gs = 0;
        for (int t = 0; t < 64; ++t) gs += h[lane * 64 + t];
        uint32_t suf = gs;
        for (int d = 1; d < 64; d <<= 1) {
            uint32_t vv = __shfl_down(suf, d);
            if (lane + d < 64) suf += vv;
        }
        unsigned long long m = __ballot(suf >= PRE);
        int G = 63 - __clzll(m);
        uint32_t A = 0;
        if (G < 63) A = __shfl(suf, G + 1);
        uint32_t hv = h[G * 64 + lane];
        uint32_t suf2 = hv;
        for (int d = 1; d < 64; d <<= 1) {
            uint32_t vv = __shfl_down(suf2, d);
            if (lane + d < 64) suf2 += vv;
        }
        unsigned long long m2 = __ballot(A + suf2 >= PRE);
        int t2 = 63 - __clzll(m2);
        if (lane == 0) cutsh = (uint32_t)(G * 64 + t2);
    }
    __syncthreads();
    uint32_t cb = cutsh;
    const float4* s = obj4 + (size_t)b * NV4;
    int t0 = blockIdx.x * 256 + threadIdx.x;
    float4 v[SCAN_ITER];
#pragma unroll
    for (int k = 0; k < SCAN_ITER; ++k) v[k] = s[t0 + k * SCAN_STRIDE];
#pragma unroll
    for (int k = 0; k < SCAN_ITER; ++k) {
        int i4 = (t0 + k * SCAN_STRIDE) * 4;
        float fv[4] = {v[k].x, v[k].y, v[k].z, v[k].w};
#pragma unroll
        for (int c = 0; c < 4; ++c) {
            uint32_t key = fkey(fv[c]);
            if ((key >> 20) >= cb) {
                uint32_t p = atomicAdd(&lcnt, 1u);
                u64 e = ((u64)key << 32) | (uint32_t)(~(uint32_t)(i4 + c));
                if (p < LBUF) buf[p] = e;
                else {
                    uint32_t g = atomicAdd(&cnt[b], 1u);
                    if (g < CAP) cand[(size_t)b * CAP + g] = e;
                }
            }
        }
    }
    __syncthreads();
    uint32_t nb = lcnt < LBUF ? lcnt : LBUF;
    if (threadIdx.x == 0) base = atomicAdd(&cnt[b], nb);
    __syncthreads();
    uint32_t bs = base;
    for (uint32_t t = threadIdx.x; t < nb; t += 256) {
        uint32_t g = bs + t;
        if (g < CAP) cand[(size_t)b * CAP + g] = buf[t];
    }
}

// ---------------- Stage 4+5: counting-rank scatter + decode ----------------
// rank_i = #{j : key_j > key_i} (keys unique via idx tie-break) — exact descending
// order without a sort. Inner stream is wave-uniform -> s_load; 2 VALU/key.
// Pads (slot >= n) map identity rank=slot so rows [n,2048) are covered exactly once.
__global__ __launch_bounds__(256) void k_rankdec(const uint32_t* __restrict__ cnt,
                                                 const u64* __restrict__ cand,
                                                 const float4* __restrict__ anchors,
                                                 const float4* __restrict__ deltas,
                                                 float4* __restrict__ boxes) {
    int b = blockIdx.x;
    int slot = blockIdx.y * 256 + threadIdx.x;   // 0..4095
    uint32_t n = cnt[b]; if (n > CAP) n = CAP;
    const u64* C = cand + (size_t)b * CAP;
    u64 mykey = (slot < (int)n) ? C[slot] : 0ull;
    int rank;
    if (slot < (int)n) {
        int r = 0;
        int j = 0;
        for (; j + 8 <= (int)n; j += 8) {   // uniform index -> s_load stream
            u64 k0 = C[j + 0], k1 = C[j + 1], k2 = C[j + 2], k3 = C[j + 3];
            u64 k4 = C[j + 4], k5 = C[j + 5], k6 = C[j + 6], k7 = C[j + 7];
            r += (k0 > mykey) + (k1 > mykey) + (k2 > mykey) + (k3 > mykey)
               + (k4 > mykey) + (k5 > mykey) + (k6 > mykey) + (k7 > mykey);
        }
        for (; j < (int)n; ++j) r += (C[j] > mykey);
        rank = r;
    } else {
        rank = slot;                        // pad rows n..4095 (only <2048 written)
    }
    if (rank < RANKP) {
        float4 outb = make_float4(0.f, 0.f, 0.f, 0.f);
        if (slot < (int)n && rank < PRE) {
            uint32_t idx = ~(uint32_t)mykey;
            if (idx < N) {
                float4 a = anchors[idx];
                float4 d = deltas[(size_t)b * N + idx];
                float w = a.z - a.x, h = a.w - a.y;
                float cx = a.x + 0.5f * w, cy = a.y + 0.5f * h;
                float dw = fminf(d.z, (float)XCLIP);
                float dh = fminf(d.w, (float)XCLIP);
                float pcx = d.x * w + cx, pcy = d.y * h + cy;
                float pw = expf(dw) * w, ph = expf(dh) * h;
                float x1 = pcx - 0.5f * pw, y1 = pcy - 0.5f * ph;
                float x2 = pcx + 0.5f * pw, y2 = pcy + 0.5f * ph;
                x1 = fminf(fmaxf(x1, 0.f), 1024.f);
                y1 = fminf(fmaxf(y1, 0.f), 1024.f);
                x2 = fminf(fmaxf(x2, 0.f), 1024.f);
                y2 = fminf(fmaxf(y2, 0.f), 1024.f);
                outb = make_float4(x1, y1, x2, y2);
            }
        }
        boxes[(size_t)b * RANKP + rank] = outb;
    }
}

// ---------------- Stage 6a: pairwise suppression bitmask + valid mask ----------------
// Diagonal blocks (ti==tj) also write diagd and the per-word valid mask
// (ballot of "box not small" — identical predicate to the reference's keep init).
#define NTRI (NWORD * (NWORD + 1) / 2)   // 528
__global__ void k_mask(const float4* __restrict__ boxes, u64* __restrict__ sup,
                       u64* __restrict__ diagd, u64* __restrict__ valid) {
    int b = blockIdx.x;
    int L = blockIdx.y;
    int ti = 0, rem = L;
    while (rem >= NWORD - ti) { rem -= NWORD - ti; ++ti; }
    int tj = ti + rem;
    __shared__ float4 jb[64];
    __shared__ float ja[64];
    int t = threadIdx.x;  // 64 threads
    const float4* bx = boxes + (size_t)b * RANKP;
    float4 v = bx[tj * 64 + t];
    jb[t] = v;
    ja[t] = (v.z - v.x) * (v.w - v.y);
    int i = ti * 64 + t;
    float4 bi = bx[i];
    float ai = (bi.z - bi.x) * (bi.w - bi.y);
    __syncthreads();
    u64 word = 0;
    for (int jj = 0; jj < 64; ++jj) {
        int j = tj * 64 + jj;
        float4 bj = jb[jj];
        float xx1 = fmaxf(bi.x, bj.x), yy1 = fmaxf(bi.y, bj.y);
        float xx2 = fminf(bi.z, bj.z), yy2 = fminf(bi.w, bj.w);
        float iw = fmaxf(xx2 - xx1, 0.f), ih = fmaxf(yy2 - yy1, 0.f);
        float inter = iw * ih;
        float iou = inter / (ai + ja[jj] - inter);
        if (j > i && iou > NMS_T) word |= 1ull << jj;
    }
    sup[((size_t)b * RANKP + i) * NWORD + tj] = word;
    if (ti == tj) {
        diagd[((size_t)b * NWORD + ti) * 64 + t] = word;
        bool ok = !((bi.z - bi.x < 1e-3f) || (bi.w - bi.y < 1e-3f));
        u64 bal = __ballot(ok);
        if (t == 0) valid[(size_t)b * NWORD + ti] = bal;
    }
}

// ---------------- Stage 6b+7: chunked greedy NMS, asm-read LDS pipeline ----------------
// ALL reads of DMA'd LDS go through inline asm (33 ds_read_b64 + lgkmcnt(0) in ONE
// block) so the compiler never inserts its conservative vmcnt(0) drain — our counted
// vmcnt(16) is the only DMA wait: ring of 3, issue-ahead-2 => ~2 chunk-times of cover.
// sup lower-triangle words (w < row's chunk) are NEVER written (0xAA poison) — the
// `lane >= c` guard keeps them out of remv. Do not remove it.
#define QLIST(X) X(0) X(1) X(2) X(3) X(4) X(5) X(6) X(7) X(8) X(9) X(10) X(11) \
    X(12) X(13) X(14) X(15) X(16) X(17) X(18) X(19) X(20) X(21) X(22) X(23)    \
    X(24) X(25) X(26) X(27) X(28) X(29) X(30) X(31)

__global__ __launch_bounds__(64, 1) void k_nms(const u64* __restrict__ valid,
                                               const u64* __restrict__ sup,
                                               const u64* __restrict__ diagd,
                                               const float4* __restrict__ boxes,
                                               float4* __restrict__ out) {
    __shared__ u64 Dg[NWORD * 64];      // 16 KiB: all 32 diagonal tiles
    __shared__ u64 Bf[3][64 * NWORD];   // 3 x 16 KiB chunk ring buffer
    int b = blockIdx.x;
    int lane = threadIdx.x;             // 64
    int w = lane & 31, hh = lane >> 5;
    const u64* S = sup + (size_t)b * RANKP * NWORD;
    u64 remv = (lane < 32) ? ~valid[(size_t)b * NWORD + lane] : 0ull;
    asm volatile("" :: "v"((uint32_t)remv), "v"((uint32_t)(remv >> 32)));
    // prologue: DMA Dg (16) + batch0 (16) + batch1 (16) = 48 outstanding (<63)
    {
        const char* gd = (const char*)(diagd + (size_t)b * (NWORD * 64));
        char* ld = (char*)&Dg[0];
#pragma unroll
        for (int i = 0; i < 16; ++i)
            gload_lds16(gd + i * 1024 + lane * 16, ld + i * 1024);
#pragma unroll
        for (int t = 0; t < 2; ++t) {
            const char* gn = (const char*)(S + (size_t)t * 64 * NWORD);
            char* lb = (char*)&Bf[t][0];
#pragma unroll
            for (int i = 0; i < 16; ++i)
                gload_lds16(gn + i * 1024 + lane * 16, lb + i * 1024);
        }
    }
    asm volatile("s_waitcnt vmcnt(16)" ::: "memory");   // Dg + batch0 done; batch1 in flight
    int kept_cnt = 0;
    for (int c = 0; c < NWORD; ++c) {
        int buf = c % 3;
        uint32_t dga = lds_addr(&Dg[(c << 6) + lane]);
        uint32_t bfa = lds_addr(&Bf[buf][(hh * 32) * NWORD + w]);
        u64 dcur;
#define DECLQ(i) u64 q##i;
        QLIST(DECLQ)
#undef DECLQ
        asm volatile(
            "ds_read_b64 %[d], %[da]\n\t"
            "ds_read_b64 %[q0], %[ba]\n\t"
            "ds_read_b64 %[q1], %[ba] offset:256\n\t"
            "ds_read_b64 %[q2], %[ba] offset:512\n\t"
            "ds_read_b64 %[q3], %[ba] offset:768\n\t"
            "ds_read_b64 %[q4], %[ba] offset:1024\n\t"
            "ds_read_b64 %[q5], %[ba] offset:1280\n\t"
            "ds_read_b64 %[q6], %[ba] offset:1536\n\t"
            "ds_read_b64 %[q7], %[ba] offset:1792\n\t"
            "ds_read_b64 %[q8], %[ba] offset:2048\n\t"
            "ds_read_b64 %[q9], %[ba] offset:2304\n\t"
            "ds_read_b64 %[q10], %[ba] offset:2560\n\t"
            "ds_read_b64 %[q11], %[ba] offset:2816\n\t"
            "ds_read_b64 %[q12], %[ba] offset:3072\n\t"
            "ds_read_b64 %[q13], %[ba] offset:3328\n\t"
            "ds_read_b64 %[q14], %[ba] offset:3584\n\t"
            "ds_read_b64 %[q15], %[ba] offset:3840\n\t"
            "ds_read_b64 %[q16], %[ba] offset:4096\n\t"
            "ds_read_b64 %[q17], %[ba] offset:4352\n\t"
            "ds_read_b64 %[q18], %[ba] offset:4608\n\t"
            "ds_read_b64 %[q19], %[ba] offset:4864\n\t"
            "ds_read_b64 %[q20], %[ba] offset:5120\n\t"
            "ds_read_b64 %[q21], %[ba] offset:5376\n\t"
            "ds_read_b64 %[q22], %[ba] offset:5632\n\t"
            "ds_read_b64 %[q23], %[ba] offset:5888\n\t"
            "ds_read_b64 %[q24], %[ba] offset:6144\n\t"
            "ds_read_b64 %[q25], %[ba] offset:6400\n\t"
            "ds_read_b64 %[q26], %[ba] offset:6656\n\t"
            "ds_read_b64 %[q27], %[ba] offset:6912\n\t"
            "ds_read_b64 %[q28], %[ba] offset:7168\n\t"
            "ds_read_b64 %[q29], %[ba] offset:7424\n\t"
            "ds_read_b64 %[q30], %[ba] offset:7680\n\t"
            "ds_read_b64 %[q31], %[ba] offset:7936\n\t"
            "s_waitcnt lgkmcnt(0)"
            : [d]"=&v"(dcur),
              [q0]"=&v"(q0), [q1]"=&v"(q1), [q2]"=&v"(q2), [q3]"=&v"(q3),
              [q4]"=&v"(q4), [q5]"=&v"(q5), [q6]"=&v"(q6), [q7]"=&v"(q7),
              [q8]"=&v"(q8), [q9]"=&v"(q9), [q10]"=&v"(q10), [q11]"=&v"(q11),
              [q12]"=&v"(q12), [q13]"=&v"(q13), [q14]"=&v"(q14), [q15]"=&v"(q15),
              [q16]"=&v"(q16), [q17]"=&v"(q17), [q18]"=&v"(q18), [q19]"=&v"(q19),
              [q20]"=&v"(q20), [q21]"=&v"(q21), [q22]"=&v"(q22), [q23]"=&v"(q23),
              [q24]"=&v"(q24), [q25]"=&v"(q25), [q26]"=&v"(q26), [q27]"=&v"(q27),
              [q28]"=&v"(q28), [q29]"=&v"(q29), [q30]"=&v"(q30), [q31]"=&v"(q31)
            : [da]"v"(dga), [ba]"v"(bfa)
            : "memory");
        // ---- step1: serial scalar recurrence on diagonal tile ----
        u64 scur = readlane_u64(remv, c);
#pragma unroll
        for (int g = 0; g < 4; ++g) {
            u64 d[16];
#pragma unroll
            for (int i = 0; i < 16; ++i) d[i] = readlane_u64(dcur, g * 16 + i);
#pragma unroll
            for (int i = 0; i < 16; ++i) {
                int row = g * 16 + i;
                if (!((scur >> row) & 1ull)) scur |= d[i];
            }
        }
        u64 kept = ~scur;
        // ---- step2: OR kept rows into remv (branchless, from asm-read registers) ----
        uint32_t kk = hh ? (uint32_t)(kept >> 32) : (uint32_t)kept;
        u64 acc = 0;
#define ACCQ(i) { u64 m = (u64)(int64_t)((int32_t)(kk << (31 - i)) >> 31); acc |= q##i & m; }
        QLIST(ACCQ)
#undef ACCQ
        u64 acco = __shfl(acc, lane + 32);
        if (lane < 32 && lane >= c) remv |= (acc | acco);
        kept_cnt += (int)__popcll(kept);
        // ---- issue batch c+2 into slot (c+2)%3 (that chunk's slot, already consumed) ----
        {
            int cn = (c + 2) & (NWORD - 1);   // wrapped issues never read; counts stay fixed
            const char* gn = (const char*)(S + (size_t)cn * 64 * NWORD);
            char* lb = (char*)&Bf[(c + 2) % 3][0];
#pragma unroll
            for (int i = 0; i < 16; ++i)
                gload_lds16(gn + i * 1024 + lane * 16, lb + i * 1024);
        }
        asm volatile("s_waitcnt vmcnt(16)" ::: "memory");  // batch c+1 complete
        if (kept_cnt >= POST) break;
    }
    // ---- epilogue: stable partition (kept first) -> top-1000 gather ----
    int tot = 0;
    for (int ww = 0; ww < NWORD; ++ww)
        tot += (int)__popcll(~readlane_u64(remv, ww));
    u64 below = (1ull << lane) - 1ull;
    int kcum = 0, ucum = 0;
    for (int ww = 0; ww < NWORD; ++ww) {
        u64 kw = ~readlane_u64(remv, ww);
        int pc = (int)__popcll(kw);
        bool kp = (kw >> lane) & 1ull;
        int pos;
        if (kp) pos = kcum + (int)__popcll(kw & below);
        else    pos = tot + ucum + (int)__popcll((~kw) & below);
        if (pos < POST) out[(size_t)b * POST + pos] = boxes[(size_t)b * RANKP + ww * 64 + lane];
        kcum += pc;
        ucum += 64 - pc;
    }
}

extern "C" void kernel_launch(void* const* d_in, const int* in_sizes, int n_in,
                              void* d_out, int out_size, void* d_ws, size_t ws_size,
                              hipStream_t stream) {
    const float* anchors = (const float*)d_in[0];   // [N,4]
    const float* obj     = (const float*)d_in[1];   // [B,N]
    const float* deltas  = (const float*)d_in[2];   // [B,N,4]
    char* ws = (char*)d_ws;

    uint32_t* hist   = (uint32_t*)(ws + 0);        // 131072
    uint32_t* cnt    = (uint32_t*)(ws + 131072);   // 256
    u64*      cand   = (u64*)(ws + 131584);        // B*4096*8 = 262144 -> 393728
    float4*   boxes  = (float4*)(ws + 393728);     // B*2048*16 = 524288 -> 918016
    u64*      valid  = (u64*)(ws + 918016);        // 2048 -> 920064
    u64*      sup    = (u64*)(ws + 920064);        // B*2048*32*8 = 4194304 -> 5114368
    u64*      diagd  = (u64*)(ws + 5114368);       // B*32*64*8 = 131072 -> 5245440

    hipMemsetAsync(ws, 0, 131328, stream);  // hist + cnt

    dim3 gscan(SCAN_BLOCKS, B);
    k_hist<<<gscan, 256, 0, stream>>>((const float4*)obj, hist);
    k_compact<<<gscan, 256, 0, stream>>>((const float4*)obj, hist, cnt, cand);
    dim3 grank(B, CAP / 256);
    k_rankdec<<<grank, 256, 0, stream>>>(cnt, cand, (const float4*)anchors,
                                         (const float4*)deltas, boxes);
    dim3 gmask(B, NTRI);
    k_mask<<<gmask, 64, 0, stream>>>(boxes, sup, diagd, valid);
    k_nms<<<B, 64, 0, stream>>>(valid, sup, diagd, boxes, (float4*)d_out);
}

// Round 12
// 131.221 us; speedup vs baseline: 1.1188x; 1.1188x over previous
//
#include <hip/hip_runtime.h>
#include <stdint.h>

#define B 8
#define N 460800
#define NV4 115200          // N/4 float4 scores per image
#define PRE 2000
#define POST 1000
#define CAP 4096
#define NBIN 4096
#define RANKP 2048
#define NWORD 32
#define NMS_T 0.7f
#define XCLIP 4.135166556742356

#define SCAN_BLOCKS 45      // 45*256*10 = 115200
#define SCAN_ITER 10
#define SCAN_STRIDE (SCAN_BLOCKS * 256)

typedef unsigned long long u64;

__device__ __forceinline__ uint32_t fkey(float f) {
    uint32_t u = __float_as_uint(f);
    return (u & 0x80000000u) ? ~u : (u | 0x80000000u);
}

__device__ __forceinline__ u64 readlane_u64(u64 v, int lane) {
    uint32_t lo = __builtin_amdgcn_readlane((uint32_t)v, lane);
    uint32_t hi = __builtin_amdgcn_readlane((uint32_t)(v >> 32), lane);
    return ((u64)hi << 32) | lo;
}

// ---------------- Stage 1: per-image histogram of score keys (top 12 bits) ----------------
__global__ __launch_bounds__(256) void k_hist(const float4* __restrict__ obj4,
                                              uint32_t* __restrict__ hist) {
    __shared__ uint32_t lh[2][NBIN];   // 32 KiB, 2-way replicated to cut contention
    int b = blockIdx.y;
    for (int i = threadIdx.x; i < NBIN; i += 256) { lh[0][i] = 0; lh[1][i] = 0; }
    __syncthreads();
    const float4* s = obj4 + (size_t)b * NV4;
    int t0 = blockIdx.x * 256 + threadIdx.x;
    uint32_t* h = lh[threadIdx.x & 1];
    float4 v[SCAN_ITER];
#pragma unroll
    for (int k = 0; k < SCAN_ITER; ++k) v[k] = s[t0 + k * SCAN_STRIDE];
#pragma unroll
    for (int k = 0; k < SCAN_ITER; ++k) {
        atomicAdd(&h[fkey(v[k].x) >> 20], 1u);
        atomicAdd(&h[fkey(v[k].y) >> 20], 1u);
        atomicAdd(&h[fkey(v[k].z) >> 20], 1u);
        atomicAdd(&h[fkey(v[k].w) >> 20], 1u);
    }
    __syncthreads();
    uint32_t* gh = hist + (size_t)b * NBIN;
    for (int i = threadIdx.x; i < NBIN; i += 256) {
        uint32_t s2 = lh[0][i] + lh[1][i];
        if (s2) atomicAdd(&gh[i], s2);
    }
}

// ---------------- Stage 2+3 fused: wave 0 computes cutoff bin, then compact ------------
#define LBUF 2048
__global__ __launch_bounds__(256) void k_compact(const float4* __restrict__ obj4,
                                                 const uint32_t* __restrict__ hist,
                                                 uint32_t* __restrict__ cnt,
                                                 u64* __restrict__ cand) {
    __shared__ u64 buf[LBUF];          // 16 KiB
    __shared__ uint32_t lcnt, base, cutsh;
    int b = blockIdx.y;
    if (threadIdx.x == 0) lcnt = 0;
    if (threadIdx.x < 64) {
        int lane = threadIdx.x;
        const uint32_t* h = hist + (size_t)b * NBIN;
        uint32_t gs = 0;
        for (int t = 0; t < 64; ++t) gs += h[lane * 64 + t];
        uint32_t suf = gs;
        for (int d = 1; d < 64; d <<= 1) {
            uint32_t vv = __shfl_down(suf, d);
            if (lane + d < 64) suf += vv;
        }
        unsigned long long m = __ballot(suf >= PRE);
        int G = 63 - __clzll(m);
        uint32_t A = 0;
        if (G < 63) A = __shfl(suf, G + 1);
        uint32_t hv = h[G * 64 + lane];
        uint32_t suf2 = hv;
        for (int d = 1; d < 64; d <<= 1) {
            uint32_t vv = __shfl_down(suf2, d);
            if (lane + d < 64) suf2 += vv;
        }
        unsigned long long m2 = __ballot(A + suf2 >= PRE);
        int t2 = 63 - __clzll(m2);
        if (lane == 0) cutsh = (uint32_t)(G * 64 + t2);
    }
    __syncthreads();
    uint32_t cb = cutsh;
    const float4* s = obj4 + (size_t)b * NV4;
    int t0 = blockIdx.x * 256 + threadIdx.x;
    float4 v[SCAN_ITER];
#pragma unroll
    for (int k = 0; k < SCAN_ITER; ++k) v[k] = s[t0 + k * SCAN_STRIDE];
#pragma unroll
    for (int k = 0; k < SCAN_ITER; ++k) {
        int i4 = (t0 + k * SCAN_STRIDE) * 4;
        float fv[4] = {v[k].x, v[k].y, v[k].z, v[k].w};
#pragma unroll
        for (int c = 0; c < 4; ++c) {
            uint32_t key = fkey(fv[c]);
            if ((key >> 20) >= cb) {
                uint32_t p = atomicAdd(&lcnt, 1u);
                u64 e = ((u64)key << 32) | (uint32_t)(~(uint32_t)(i4 + c));
                if (p < LBUF) buf[p] = e;
                else {
                    uint32_t g = atomicAdd(&cnt[b], 1u);
                    if (g < CAP) cand[(size_t)b * CAP + g] = e;
                }
            }
        }
    }
    __syncthreads();
    uint32_t nb = lcnt < LBUF ? lcnt : LBUF;
    if (threadIdx.x == 0) base = atomicAdd(&cnt[b], nb);
    __syncthreads();
    uint32_t bs = base;
    for (uint32_t t = threadIdx.x; t < nb; t += 256) {
        uint32_t g = bs + t;
        if (g < CAP) cand[(size_t)b * CAP + g] = buf[t];
    }
}

// ---------------- Stage 4+5: counting-rank (readlane broadcast) + decode ----------------
// rank_i = #{j : key_j > key_i} (keys unique via idx tie-break). One wave per 64 slots;
// j-stream loaded COALESCED per-lane (vector loads, fully pipelined), broadcast to all
// lanes via v_readlane — no SMEM/LDS, no wait-drain in the chain. 4 VALU/key.
__global__ __launch_bounds__(64) void k_rankdec(const uint32_t* __restrict__ cnt,
                                                const u64* __restrict__ cand,
                                                const float4* __restrict__ anchors,
                                                const float4* __restrict__ deltas,
                                                float4* __restrict__ boxes) {
    int b = blockIdx.x;
    int lane = threadIdx.x;                       // 64
    int slot = blockIdx.y * 64 + lane;            // 0..4095
    uint32_t n = cnt[b]; if (n > CAP) n = CAP;
    const u64* C = cand + (size_t)b * CAP;
    u64 mykey = (slot < (int)n) ? C[slot] : 0ull;
    int r = 0;
    int ng = ((int)n + 63) >> 6;
    for (int g = 0; g < ng; ++g) {
        int j = g * 64 + lane;
        u64 kv = (j < (int)n) ? C[j] : 0ull;      // coalesced; 0 never counts (keys huge)
#pragma unroll
        for (int t = 0; t < 64; ++t) {
            u64 k = readlane_u64(kv, t);
            r += (k > mykey) ? 1 : 0;
        }
    }
    int rank = (slot < (int)n) ? r : slot;        // pads cover rows [n,2048) bijectively
    if (rank < RANKP) {
        float4 outb = make_float4(0.f, 0.f, 0.f, 0.f);
        if (slot < (int)n && rank < PRE) {
            uint32_t idx = ~(uint32_t)mykey;
            if (idx < N) {
                float4 a = anchors[idx];
                float4 d = deltas[(size_t)b * N + idx];
                float w = a.z - a.x, h = a.w - a.y;
                float cx = a.x + 0.5f * w, cy = a.y + 0.5f * h;
                float dw = fminf(d.z, (float)XCLIP);
                float dh = fminf(d.w, (float)XCLIP);
                float pcx = d.x * w + cx, pcy = d.y * h + cy;
                float pw = expf(dw) * w, ph = expf(dh) * h;
                float x1 = pcx - 0.5f * pw, y1 = pcy - 0.5f * ph;
                float x2 = pcx + 0.5f * pw, y2 = pcy + 0.5f * ph;
                x1 = fminf(fmaxf(x1, 0.f), 1024.f);
                y1 = fminf(fmaxf(y1, 0.f), 1024.f);
                x2 = fminf(fmaxf(x2, 0.f), 1024.f);
                y2 = fminf(fmaxf(y2, 0.f), 1024.f);
                outb = make_float4(x1, y1, x2, y2);
            }
        }
        boxes[(size_t)b * RANKP + rank] = outb;
    }
}

// ---------------- Stage 6a: pairwise suppression bitmask + diag + valid ----------------
#define NTRI (NWORD * (NWORD + 1) / 2)   // 528
__global__ void k_mask(const float4* __restrict__ boxes, u64* __restrict__ sup,
                       u64* __restrict__ diagd, u64* __restrict__ valid) {
    int b = blockIdx.x;
    int L = blockIdx.y;
    int ti = 0, rem = L;
    while (rem >= NWORD - ti) { rem -= NWORD - ti; ++ti; }
    int tj = ti + rem;
    __shared__ float4 jb[64];
    __shared__ float ja[64];
    int t = threadIdx.x;  // 64 threads
    const float4* bx = boxes + (size_t)b * RANKP;
    float4 v = bx[tj * 64 + t];
    jb[t] = v;
    ja[t] = (v.z - v.x) * (v.w - v.y);
    int i = ti * 64 + t;
    float4 bi = bx[i];
    float ai = (bi.z - bi.x) * (bi.w - bi.y);
    __syncthreads();
    u64 word = 0;
    for (int jj = 0; jj < 64; ++jj) {
        int j = tj * 64 + jj;
        float4 bj = jb[jj];
        float xx1 = fmaxf(bi.x, bj.x), yy1 = fmaxf(bi.y, bj.y);
        float xx2 = fminf(bi.z, bj.z), yy2 = fminf(bi.w, bj.w);
        float iw = fmaxf(xx2 - xx1, 0.f), ih = fmaxf(yy2 - yy1, 0.f);
        float inter = iw * ih;
        float iou = inter / (ai + ja[jj] - inter);
        if (j > i && iou > NMS_T) word |= 1ull << jj;
    }
    sup[((size_t)b * RANKP + i) * NWORD + tj] = word;
    if (ti == tj) {
        diagd[((size_t)b * NWORD + ti) * 64 + t] = word;
        bool ok = !((bi.z - bi.x < 1e-3f) || (bi.w - bi.y < 1e-3f));
        u64 bal = __ballot(ok);
        if (t == 0) valid[(size_t)b * NWORD + ti] = bal;
    }
}

// ---------------- Stage 6b+7: chunked greedy NMS, pure-register asm pipeline ----------------
// NO LDS, NO SMEM: rows (32 u64) + diag word per chunk live in named registers, loaded
// by inline-asm global_load_dwordx2 (A/B double buffer). Unroll-2 loop: issue next batch
// -> compute current (~700cy, covers L3 latency) -> vmcnt(0)+sched_barrier (exactly one
// batch outstanding; nothing else can drain it — no compiler-inserted waits possible).
// sup lower-triangle words (w < row's chunk) are NEVER written (0xAA poison from the
// harness) — the `lane >= c` guard keeps them out of remv. Do not remove it.
#define QLIST(X) X(0) X(1) X(2) X(3) X(4) X(5) X(6) X(7) X(8) X(9) X(10) X(11) \
    X(12) X(13) X(14) X(15) X(16) X(17) X(18) X(19) X(20) X(21) X(22) X(23)    \
    X(24) X(25) X(26) X(27) X(28) X(29) X(30) X(31)

#define DECLA(i) u64 A##i;
#define DECLB(i) u64 B##i;
#define ACCA(i) { u64 m_ = (u64)(int64_t)((int32_t)(kk << (31 - i)) >> 31); acc |= A##i & m_; }
#define ACCB(i) { u64 m_ = (u64)(int64_t)((int32_t)(kk << (31 - i)) >> 31); acc |= B##i & m_; }

#define ISSUE_ROWS(P, CC) do {                                                        \
    const char* g1_ = (const char*)S + ((size_t)((CC) & (NWORD - 1)) << 14);          \
    const char* g2_ = g1_ + 4096;                                                     \
    const char* gd_ = (const char*)Dv + ((size_t)((CC) & (NWORD - 1)) << 9);          \
    asm volatile(                                                                     \
        "global_load_dwordx2 %[q0], %[vo], %[sp] offset:0\n\t"                        \
        "global_load_dwordx2 %[q1], %[vo], %[sp] offset:256\n\t"                      \
        "global_load_dwordx2 %[q2], %[vo], %[sp] offset:512\n\t"                      \
        "global_load_dwordx2 %[q3], %[vo], %[sp] offset:768\n\t"                      \
        "global_load_dwordx2 %[q4], %[vo], %[sp] offset:1024\n\t"                     \
        "global_load_dwordx2 %[q5], %[vo], %[sp] offset:1280\n\t"                     \
        "global_load_dwordx2 %[q6], %[vo], %[sp] offset:1536\n\t"                     \
        "global_load_dwordx2 %[q7], %[vo], %[sp] offset:1792\n\t"                     \
        "global_load_dwordx2 %[q8], %[vo], %[sp] offset:2048\n\t"                     \
        "global_load_dwordx2 %[q9], %[vo], %[sp] offset:2304\n\t"                     \
        "global_load_dwordx2 %[q10], %[vo], %[sp] offset:2560\n\t"                    \
        "global_load_dwordx2 %[q11], %[vo], %[sp] offset:2816\n\t"                    \
        "global_load_dwordx2 %[q12], %[vo], %[sp] offset:3072\n\t"                    \
        "global_load_dwordx2 %[q13], %[vo], %[sp] offset:3328\n\t"                    \
        "global_load_dwordx2 %[q14], %[vo], %[sp] offset:3584\n\t"                    \
        "global_load_dwordx2 %[q15], %[vo], %[sp] offset:3840\n\t"                    \
        : [q0]"=&v"(P##0), [q1]"=&v"(P##1), [q2]"=&v"(P##2), [q3]"=&v"(P##3),         \
          [q4]"=&v"(P##4), [q5]"=&v"(P##5), [q6]"=&v"(P##6), [q7]"=&v"(P##7),         \
          [q8]"=&v"(P##8), [q9]"=&v"(P##9), [q10]"=&v"(P##10), [q11]"=&v"(P##11),     \
          [q12]"=&v"(P##12), [q13]"=&v"(P##13), [q14]"=&v"(P##14), [q15]"=&v"(P##15)  \
        : [vo]"v"(voff), [sp]"s"(g1_));                                               \
    asm volatile(                                                                     \
        "global_load_dwordx2 %[q16], %[vo], %[sp] offset:0\n\t"                       \
        "global_load_dwordx2 %[q17], %[vo], %[sp] offset:256\n\t"                     \
        "global_load_dwordx2 %[q18], %[vo], %[sp] offset:512\n\t"                     \
        "global_load_dwordx2 %[q19], %[vo], %[sp] offset:768\n\t"                     \
        "global_load_dwordx2 %[q20], %[vo], %[sp] offset:1024\n\t"                    \
        "global_load_dwordx2 %[q21], %[vo], %[sp] offset:1280\n\t"                    \
        "global_load_dwordx2 %[q22], %[vo], %[sp] offset:1536\n\t"                    \
        "global_load_dwordx2 %[q23], %[vo], %[sp] offset:1792\n\t"                    \
        "global_load_dwordx2 %[q24], %[vo], %[sp] offset:2048\n\t"                    \
        "global_load_dwordx2 %[q25], %[vo], %[sp] offset:2304\n\t"                    \
        "global_load_dwordx2 %[q26], %[vo], %[sp] offset:2560\n\t"                    \
        "global_load_dwordx2 %[q27], %[vo], %[sp] offset:2816\n\t"                    \
        "global_load_dwordx2 %[q28], %[vo], %[sp] offset:3072\n\t"                    \
        "global_load_dwordx2 %[q29], %[vo], %[sp] offset:3328\n\t"                    \
        "global_load_dwordx2 %[q30], %[vo], %[sp] offset:3584\n\t"                    \
        "global_load_dwordx2 %[q31], %[vo], %[sp] offset:3840\n\t"                    \
        "global_load_dwordx2 %[qd], %[vd], %[sd] offset:0\n\t"                        \
        : [q16]"=&v"(P##16), [q17]"=&v"(P##17), [q18]"=&v"(P##18), [q19]"=&v"(P##19), \
          [q20]"=&v"(P##20), [q21]"=&v"(P##21), [q22]"=&v"(P##22), [q23]"=&v"(P##23), \
          [q24]"=&v"(P##24), [q25]"=&v"(P##25), [q26]"=&v"(P##26), [q27]"=&v"(P##27), \
          [q28]"=&v"(P##28), [q29]"=&v"(P##29), [q30]"=&v"(P##30), [q31]"=&v"(P##31), \
          [qd]"=&v"(P##d)                                                             \
        : [vo]"v"(voff), [sp]"s"(g2_), [vd]"v"(vdiag), [sd]"s"(gd_));                 \
} while (0)

#define WAITV0() do { asm volatile("s_waitcnt vmcnt(0)" ::: "memory");                \
                      __builtin_amdgcn_sched_barrier(0); } while (0)

#define NMS_BODY(ACCM, DREG, CC) do {                                                 \
    int cc_ = (CC);                                                                   \
    u64 dcur_ = (DREG);                                                               \
    u64 scur = readlane_u64(remv, cc_);                                               \
    _Pragma("unroll") for (int g = 0; g < 4; ++g) {                                   \
        u64 dd[16];                                                                   \
        _Pragma("unroll") for (int i = 0; i < 16; ++i)                                \
            dd[i] = readlane_u64(dcur_, g * 16 + i);                                  \
        _Pragma("unroll") for (int i = 0; i < 16; ++i) {                              \
            int row = g * 16 + i;                                                     \
            if (!((scur >> row) & 1ull)) scur |= dd[i];                               \
        }                                                                             \
    }                                                                                 \
    u64 kept = ~scur;                                                                 \
    uint32_t kk = hh ? (uint32_t)(kept >> 32) : (uint32_t)kept;                       \
    u64 acc = 0;                                                                      \
    QLIST(ACCM)                                                                       \
    u64 acco = __shfl(acc, lane + 32);                                                \
    if (lane < 32 && lane >= cc_) remv |= (acc | acco);                               \
    kept_cnt += (int)__popcll(kept);                                                  \
} while (0)

__global__ __launch_bounds__(64, 1) void k_nms(const u64* __restrict__ valid,
                                               const u64* __restrict__ sup,
                                               const u64* __restrict__ diagd,
                                               const float4* __restrict__ boxes,
                                               float4* __restrict__ out) {
    int b = blockIdx.x;
    int lane = threadIdx.x;             // 64
    int w = lane & 31, hh = lane >> 5;
    const u64* S = sup + (size_t)b * RANKP * NWORD;
    const u64* Dv = diagd + (size_t)b * (NWORD * 64);
    uint32_t voff  = (uint32_t)(hh * 8192 + w * 8);   // rows hh*32..hh*32+15 via imm
    uint32_t vdiag = (uint32_t)(lane * 8);
    u64 remv = (lane < 32) ? ~valid[(size_t)b * NWORD + lane] : 0ull;
    QLIST(DECLA) u64 Ad;
    QLIST(DECLB) u64 Bd;
    int kept_cnt = 0;
    ISSUE_ROWS(A, 0);
    WAITV0();
    for (int c = 0; c < NWORD; c += 2) {
        ISSUE_ROWS(B, c + 1);
        NMS_BODY(ACCA, Ad, c);
        if (kept_cnt >= POST) goto done;
        WAITV0();
        ISSUE_ROWS(A, c + 2);
        NMS_BODY(ACCB, Bd, c + 1);
        if (kept_cnt >= POST) goto done;
        WAITV0();
    }
done: ;
    // ---- epilogue: stable partition (kept first) -> top-1000 gather ----
    int tot = 0;
    for (int ww = 0; ww < NWORD; ++ww)
        tot += (int)__popcll(~readlane_u64(remv, ww));
    u64 below = (1ull << lane) - 1ull;
    int kcum = 0, ucum = 0;
    for (int ww = 0; ww < NWORD; ++ww) {
        u64 kw = ~readlane_u64(remv, ww);
        int pc = (int)__popcll(kw);
        bool kp = (kw >> lane) & 1ull;
        int pos;
        if (kp) pos = kcum + (int)__popcll(kw & below);
        else    pos = tot + ucum + (int)__popcll((~kw) & below);
        if (pos < POST) out[(size_t)b * POST + pos] = boxes[(size_t)b * RANKP + ww * 64 + lane];
        kcum += pc;
        ucum += 64 - pc;
    }
}

extern "C" void kernel_launch(void* const* d_in, const int* in_sizes, int n_in,
                              void* d_out, int out_size, void* d_ws, size_t ws_size,
                              hipStream_t stream) {
    const float* anchors = (const float*)d_in[0];   // [N,4]
    const float* obj     = (const float*)d_in[1];   // [B,N]
    const float* deltas  = (const float*)d_in[2];   // [B,N,4]
    char* ws = (char*)d_ws;

    uint32_t* hist   = (uint32_t*)(ws + 0);        // 131072
    uint32_t* cnt    = (uint32_t*)(ws + 131072);   // 256
    u64*      cand   = (u64*)(ws + 131584);        // B*4096*8 = 262144 -> 393728
    float4*   boxes  = (float4*)(ws + 393728);     // B*2048*16 = 524288 -> 918016
    u64*      valid  = (u64*)(ws + 918016);        // 2048 -> 920064
    u64*      sup    = (u64*)(ws + 920064);        // B*2048*32*8 = 4194304 -> 5114368
    u64*      diagd  = (u64*)(ws + 5114368);       // B*32*64*8 = 131072 -> 5245440

    hipMemsetAsync(ws, 0, 131328, stream);  // hist + cnt

    dim3 gscan(SCAN_BLOCKS, B);
    k_hist<<<gscan, 256, 0, stream>>>((const float4*)obj, hist);
    k_compact<<<gscan, 256, 0, stream>>>((const float4*)obj, hist, cnt, cand);
    dim3 grank(B, CAP / 64);
    k_rankdec<<<grank, 64, 0, stream>>>(cnt, cand, (const float4*)anchors,
                                        (const float4*)deltas, boxes);
    dim3 gmask(B, NTRI);
    k_mask<<<gmask, 64, 0, stream>>>(boxes, sup, diagd, valid);
    k_nms<<<B, 64, 0, stream>>>(valid, sup, diagd, boxes, (float4*)d_out);
}

// Round 13
// 110.537 us; speedup vs baseline: 1.3281x; 1.1871x over previous
//
#include <hip/hip_runtime.h>
#include <stdint.h>

#define B 8
#define N 460800
#define NV4 115200          // N/4 float4 scores per image
#define PRE 2000
#define POST 1000
#define CAP 4096
#define NBIN 4096
#define RANKP 2048
#define NWORD 32
#define NMS_T 0.7f
#define XCLIP 4.135166556742356

#define SCAN_BLOCKS 45      // 45*256*10 = 115200
#define SCAN_ITER 10
#define SCAN_STRIDE (SCAN_BLOCKS * 256)

typedef unsigned long long u64;

__device__ __forceinline__ uint32_t fkey(float f) {
    uint32_t u = __float_as_uint(f);
    return (u & 0x80000000u) ? ~u : (u | 0x80000000u);
}

__device__ __forceinline__ u64 readlane_u64(u64 v, int lane) {
    uint32_t lo = __builtin_amdgcn_readlane((uint32_t)v, lane);
    uint32_t hi = __builtin_amdgcn_readlane((uint32_t)(v >> 32), lane);
    return ((u64)hi << 32) | lo;
}

// ---------------- Stage 1: per-image histogram of score keys (top 12 bits) ----------------
__global__ __launch_bounds__(256) void k_hist(const float4* __restrict__ obj4,
                                              uint32_t* __restrict__ hist) {
    __shared__ uint32_t lh[2][NBIN];   // 32 KiB, 2-way replicated to cut contention
    int b = blockIdx.y;
    for (int i = threadIdx.x; i < NBIN; i += 256) { lh[0][i] = 0; lh[1][i] = 0; }
    __syncthreads();
    const float4* s = obj4 + (size_t)b * NV4;
    int t0 = blockIdx.x * 256 + threadIdx.x;
    uint32_t* h = lh[threadIdx.x & 1];
    float4 v[SCAN_ITER];
#pragma unroll
    for (int k = 0; k < SCAN_ITER; ++k) v[k] = s[t0 + k * SCAN_STRIDE];
#pragma unroll
    for (int k = 0; k < SCAN_ITER; ++k) {
        atomicAdd(&h[fkey(v[k].x) >> 20], 1u);
        atomicAdd(&h[fkey(v[k].y) >> 20], 1u);
        atomicAdd(&h[fkey(v[k].z) >> 20], 1u);
        atomicAdd(&h[fkey(v[k].w) >> 20], 1u);
    }
    __syncthreads();
    uint32_t* gh = hist + (size_t)b * NBIN;
    for (int i = threadIdx.x; i < NBIN; i += 256) {
        uint32_t s2 = lh[0][i] + lh[1][i];
        if (s2) atomicAdd(&gh[i], s2);
    }
}

// ---------------- Stage 2+3 fused: wave 0 computes cutoff bin, then compact ------------
#define LBUF 2048
__global__ __launch_bounds__(256) void k_compact(const float4* __restrict__ obj4,
                                                 const uint32_t* __restrict__ hist,
                                                 uint32_t* __restrict__ cnt,
                                                 u64* __restrict__ cand) {
    __shared__ u64 buf[LBUF];          // 16 KiB
    __shared__ uint32_t lcnt, base, cutsh;
    int b = blockIdx.y;
    if (threadIdx.x == 0) lcnt = 0;
    if (threadIdx.x < 64) {
        int lane = threadIdx.x;
        const uint32_t* h = hist + (size_t)b * NBIN;
        uint32_t gs = 0;
        for (int t = 0; t < 64; ++t) gs += h[lane * 64 + t];
        uint32_t suf = gs;
        for (int d = 1; d < 64; d <<= 1) {
            uint32_t vv = __shfl_down(suf, d);
            if (lane + d < 64) suf += vv;
        }
        unsigned long long m = __ballot(suf >= PRE);
        int G = 63 - __clzll(m);
        uint32_t A = 0;
        if (G < 63) A = __shfl(suf, G + 1);
        uint32_t hv = h[G * 64 + lane];
        uint32_t suf2 = hv;
        for (int d = 1; d < 64; d <<= 1) {
            uint32_t vv = __shfl_down(suf2, d);
            if (lane + d < 64) suf2 += vv;
        }
        unsigned long long m2 = __ballot(A + suf2 >= PRE);
        int t2 = 63 - __clzll(m2);
        if (lane == 0) cutsh = (uint32_t)(G * 64 + t2);
    }
    __syncthreads();
    uint32_t cb = cutsh;
    const float4* s = obj4 + (size_t)b * NV4;
    int t0 = blockIdx.x * 256 + threadIdx.x;
    float4 v[SCAN_ITER];
#pragma unroll
    for (int k = 0; k < SCAN_ITER; ++k) v[k] = s[t0 + k * SCAN_STRIDE];
#pragma unroll
    for (int k = 0; k < SCAN_ITER; ++k) {
        int i4 = (t0 + k * SCAN_STRIDE) * 4;
        float fv[4] = {v[k].x, v[k].y, v[k].z, v[k].w};
#pragma unroll
        for (int c = 0; c < 4; ++c) {
            uint32_t key = fkey(fv[c]);
            if ((key >> 20) >= cb) {
                uint32_t p = atomicAdd(&lcnt, 1u);
                u64 e = ((u64)key << 32) | (uint32_t)(~(uint32_t)(i4 + c));
                if (p < LBUF) buf[p] = e;
                else {
                    uint32_t g = atomicAdd(&cnt[b], 1u);
                    if (g < CAP) cand[(size_t)b * CAP + g] = e;
                }
            }
        }
    }
    __syncthreads();
    uint32_t nb = lcnt < LBUF ? lcnt : LBUF;
    if (threadIdx.x == 0) base = atomicAdd(&cnt[b], nb);
    __syncthreads();
    uint32_t bs = base;
    for (uint32_t t = threadIdx.x; t < nb; t += 256) {
        uint32_t g = bs + t;
        if (g < CAP) cand[(size_t)b * CAP + g] = buf[t];
    }
}

// ---------------- Stage 4+5: counting-rank (readlane broadcast) + decode ----------------
// rank_i = #{j : key_j > key_i} (keys unique via idx tie-break). One wave per 64 slots;
// j-stream loaded coalesced per-lane with a 3-deep NAMED-REGISTER prefetch rotation
// (never arrays — allocator demotes those), broadcast via v_readlane; two independent
// accumulators break the VCC serialization. No SMEM/LDS anywhere in the chain.
__global__ __launch_bounds__(64) void k_rankdec(const uint32_t* __restrict__ cnt,
                                                const u64* __restrict__ cand,
                                                const float4* __restrict__ anchors,
                                                const float4* __restrict__ deltas,
                                                float4* __restrict__ boxes) {
    int b = blockIdx.x;
    int lane = threadIdx.x;                       // 64
    int slot = blockIdx.y * 64 + lane;            // 0..4095
    uint32_t n = cnt[b]; if (n > CAP) n = CAP;
    const u64* C = cand + (size_t)b * CAP;
    u64 mykey = (slot < (int)n) ? C[slot] : 0ull;
    int ng = ((int)n + 63) >> 6;
    // guarded group load: address clamped in-bounds, value masked by j<n
    auto ld = [&](int g) -> u64 {
        int j = g * 64 + lane;
        int jc = j < (CAP - 1) ? j : (CAP - 1);
        u64 kv = C[jc];
        return (j < (int)n) ? kv : 0ull;          // 0 never counts (real keys have MSB set)
    };
    u64 kv0 = ld(0), kv1 = ld(1), kv2 = ld(2);
    int r0 = 0, r1 = 0;
    for (int g = 0; g < ng; ++g) {
        u64 kvn = ld(g + 3);
#pragma unroll
        for (int t = 0; t < 64; t += 2) {
            u64 ka = readlane_u64(kv0, t);
            u64 kb = readlane_u64(kv0, t + 1);
            r0 += (ka > mykey) ? 1 : 0;
            r1 += (kb > mykey) ? 1 : 0;
        }
        kv0 = kv1; kv1 = kv2; kv2 = kvn;
    }
    int r = r0 + r1;
    int rank = (slot < (int)n) ? r : slot;        // pads cover rows [n,2048) bijectively
    if (rank < RANKP) {
        float4 outb = make_float4(0.f, 0.f, 0.f, 0.f);
        if (slot < (int)n && rank < PRE) {
            uint32_t idx = ~(uint32_t)mykey;
            if (idx < N) {
                float4 a = anchors[idx];
                float4 d = deltas[(size_t)b * N + idx];
                float w = a.z - a.x, h = a.w - a.y;
                float cx = a.x + 0.5f * w, cy = a.y + 0.5f * h;
                float dw = fminf(d.z, (float)XCLIP);
                float dh = fminf(d.w, (float)XCLIP);
                float pcx = d.x * w + cx, pcy = d.y * h + cy;
                float pw = expf(dw) * w, ph = expf(dh) * h;
                float x1 = pcx - 0.5f * pw, y1 = pcy - 0.5f * ph;
                float x2 = pcx + 0.5f * pw, y2 = pcy + 0.5f * ph;
                x1 = fminf(fmaxf(x1, 0.f), 1024.f);
                y1 = fminf(fmaxf(y1, 0.f), 1024.f);
                x2 = fminf(fmaxf(x2, 0.f), 1024.f);
                y2 = fminf(fmaxf(y2, 0.f), 1024.f);
                outb = make_float4(x1, y1, x2, y2);
            }
        }
        boxes[(size_t)b * RANKP + rank] = outb;
    }
}

// ---------------- Stage 6a: pairwise suppression bitmask + diag + valid ----------------
#define NTRI (NWORD * (NWORD + 1) / 2)   // 528
__global__ void k_mask(const float4* __restrict__ boxes, u64* __restrict__ sup,
                       u64* __restrict__ diagd, u64* __restrict__ valid) {
    int b = blockIdx.x;
    int L = blockIdx.y;
    int ti = 0, rem = L;
    while (rem >= NWORD - ti) { rem -= NWORD - ti; ++ti; }
    int tj = ti + rem;
    __shared__ float4 jb[64];
    __shared__ float ja[64];
    int t = threadIdx.x;  // 64 threads
    const float4* bx = boxes + (size_t)b * RANKP;
    float4 v = bx[tj * 64 + t];
    jb[t] = v;
    ja[t] = (v.z - v.x) * (v.w - v.y);
    int i = ti * 64 + t;
    float4 bi = bx[i];
    float ai = (bi.z - bi.x) * (bi.w - bi.y);
    __syncthreads();
    u64 word = 0;
    for (int jj = 0; jj < 64; ++jj) {
        int j = tj * 64 + jj;
        float4 bj = jb[jj];
        float xx1 = fmaxf(bi.x, bj.x), yy1 = fmaxf(bi.y, bj.y);
        float xx2 = fminf(bi.z, bj.z), yy2 = fminf(bi.w, bj.w);
        float iw = fmaxf(xx2 - xx1, 0.f), ih = fmaxf(yy2 - yy1, 0.f);
        float inter = iw * ih;
        float iou = inter / (ai + ja[jj] - inter);
        if (j > i && iou > NMS_T) word |= 1ull << jj;
    }
    sup[((size_t)b * RANKP + i) * NWORD + tj] = word;
    if (ti == tj) {
        diagd[((size_t)b * NWORD + ti) * 64 + t] = word;
        bool ok = !((bi.z - bi.x < 1e-3f) || (bi.w - bi.y < 1e-3f));
        u64 bal = __ballot(ok);
        if (t == 0) valid[(size_t)b * NWORD + ti] = bal;
    }
}

// ---------------- Stage 6b+7: chunked greedy NMS, pure-register asm pipeline ----------------
// NO LDS, NO SMEM: rows (32 u64) + diag word per chunk live in named registers, loaded
// by inline-asm global_load_dwordx2 (A/B double buffer). Unroll-2 loop: issue next batch
// -> compute current (~700cy, covers L3 latency) -> vmcnt(0)+sched_barrier (exactly one
// batch outstanding; nothing else can drain it — no compiler-inserted waits possible).
// sup lower-triangle words (w < row's chunk) are NEVER written (0xAA poison from the
// harness) — the `lane >= c` guard keeps them out of remv. Do not remove it.
#define QLIST(X) X(0) X(1) X(2) X(3) X(4) X(5) X(6) X(7) X(8) X(9) X(10) X(11) \
    X(12) X(13) X(14) X(15) X(16) X(17) X(18) X(19) X(20) X(21) X(22) X(23)    \
    X(24) X(25) X(26) X(27) X(28) X(29) X(30) X(31)

#define DECLA(i) u64 A##i;
#define DECLB(i) u64 B##i;
#define ACCA(i) { u64 m_ = (u64)(int64_t)((int32_t)(kk << (31 - i)) >> 31); acc |= A##i & m_; }
#define ACCB(i) { u64 m_ = (u64)(int64_t)((int32_t)(kk << (31 - i)) >> 31); acc |= B##i & m_; }

#define ISSUE_ROWS(P, CC) do {                                                        \
    const char* g1_ = (const char*)S + ((size_t)((CC) & (NWORD - 1)) << 14);          \
    const char* g2_ = g1_ + 4096;                                                     \
    const char* gd_ = (const char*)Dv + ((size_t)((CC) & (NWORD - 1)) << 9);          \
    asm volatile(                                                                     \
        "global_load_dwordx2 %[q0], %[vo], %[sp] offset:0\n\t"                        \
        "global_load_dwordx2 %[q1], %[vo], %[sp] offset:256\n\t"                      \
        "global_load_dwordx2 %[q2], %[vo], %[sp] offset:512\n\t"                      \
        "global_load_dwordx2 %[q3], %[vo], %[sp] offset:768\n\t"                      \
        "global_load_dwordx2 %[q4], %[vo], %[sp] offset:1024\n\t"                     \
        "global_load_dwordx2 %[q5], %[vo], %[sp] offset:1280\n\t"                     \
        "global_load_dwordx2 %[q6], %[vo], %[sp] offset:1536\n\t"                     \
        "global_load_dwordx2 %[q7], %[vo], %[sp] offset:1792\n\t"                     \
        "global_load_dwordx2 %[q8], %[vo], %[sp] offset:2048\n\t"                     \
        "global_load_dwordx2 %[q9], %[vo], %[sp] offset:2304\n\t"                     \
        "global_load_dwordx2 %[q10], %[vo], %[sp] offset:2560\n\t"                    \
        "global_load_dwordx2 %[q11], %[vo], %[sp] offset:2816\n\t"                    \
        "global_load_dwordx2 %[q12], %[vo], %[sp] offset:3072\n\t"                    \
        "global_load_dwordx2 %[q13], %[vo], %[sp] offset:3328\n\t"                    \
        "global_load_dwordx2 %[q14], %[vo], %[sp] offset:3584\n\t"                    \
        "global_load_dwordx2 %[q15], %[vo], %[sp] offset:3840\n\t"                    \
        : [q0]"=&v"(P##0), [q1]"=&v"(P##1), [q2]"=&v"(P##2), [q3]"=&v"(P##3),         \
          [q4]"=&v"(P##4), [q5]"=&v"(P##5), [q6]"=&v"(P##6), [q7]"=&v"(P##7),         \
          [q8]"=&v"(P##8), [q9]"=&v"(P##9), [q10]"=&v"(P##10), [q11]"=&v"(P##11),     \
          [q12]"=&v"(P##12), [q13]"=&v"(P##13), [q14]"=&v"(P##14), [q15]"=&v"(P##15)  \
        : [vo]"v"(voff), [sp]"s"(g1_));                                               \
    asm volatile(                                                                     \
        "global_load_dwordx2 %[q16], %[vo], %[sp] offset:0\n\t"                       \
        "global_load_dwordx2 %[q17], %[vo], %[sp] offset:256\n\t"                     \
        "global_load_dwordx2 %[q18], %[vo], %[sp] offset:512\n\t"                     \
        "global_load_dwordx2 %[q19], %[vo], %[sp] offset:768\n\t"                     \
        "global_load_dwordx2 %[q20], %[vo], %[sp] offset:1024\n\t"                    \
        "global_load_dwordx2 %[q21], %[vo], %[sp] offset:1280\n\t"                    \
        "global_load_dwordx2 %[q22], %[vo], %[sp] offset:1536\n\t"                    \
        "global_load_dwordx2 %[q23], %[vo], %[sp] offset:1792\n\t"                    \
        "global_load_dwordx2 %[q24], %[vo], %[sp] offset:2048\n\t"                    \
        "global_load_dwordx2 %[q25], %[vo], %[sp] offset:2304\n\t"                    \
        "global_load_dwordx2 %[q26], %[vo], %[sp] offset:2560\n\t"                    \
        "global_load_dwordx2 %[q27], %[vo], %[sp] offset:2816\n\t"                    \
        "global_load_dwordx2 %[q28], %[vo], %[sp] offset:3072\n\t"                    \
        "global_load_dwordx2 %[q29], %[vo], %[sp] offset:3328\n\t"                    \
        "global_load_dwordx2 %[q30], %[vo], %[sp] offset:3584\n\t"                    \
        "global_load_dwordx2 %[q31], %[vo], %[sp] offset:3840\n\t"                    \
        "global_load_dwordx2 %[qd], %[vd], %[sd] offset:0\n\t"                        \
        : [q16]"=&v"(P##16), [q17]"=&v"(P##17), [q18]"=&v"(P##18), [q19]"=&v"(P##19), \
          [q20]"=&v"(P##20), [q21]"=&v"(P##21), [q22]"=&v"(P##22), [q23]"=&v"(P##23), \
          [q24]"=&v"(P##24), [q25]"=&v"(P##25), [q26]"=&v"(P##26), [q27]"=&v"(P##27), \
          [q28]"=&v"(P##28), [q29]"=&v"(P##29), [q30]"=&v"(P##30), [q31]"=&v"(P##31), \
          [qd]"=&v"(P##d)                                                             \
        : [vo]"v"(voff), [sp]"s"(g2_), [vd]"v"(vdiag), [sd]"s"(gd_));                 \
} while (0)

#define WAITV0() do { asm volatile("s_waitcnt vmcnt(0)" ::: "memory");                \
                      __builtin_amdgcn_sched_barrier(0); } while (0)

#define NMS_BODY(ACCM, DREG, CC) do {                                                 \
    int cc_ = (CC);                                                                   \
    u64 dcur_ = (DREG);                                                               \
    u64 scur = readlane_u64(remv, cc_);                                               \
    _Pragma("unroll") for (int g = 0; g < 4; ++g) {                                   \
        u64 dd[16];                                                                   \
        _Pragma("unroll") for (int i = 0; i < 16; ++i)                                \
            dd[i] = readlane_u64(dcur_, g * 16 + i);                                  \
        _Pragma("unroll") for (int i = 0; i < 16; ++i) {                              \
            int row = g * 16 + i;                                                     \
            if (!((scur >> row) & 1ull)) scur |= dd[i];                               \
        }                                                                             \
    }                                                                                 \
    u64 kept = ~scur;                                                                 \
    uint32_t kk = hh ? (uint32_t)(kept >> 32) : (uint32_t)kept;                       \
    u64 acc = 0;                                                                      \
    QLIST(ACCM)                                                                       \
    u64 acco = __shfl(acc, lane + 32);                                                \
    if (lane < 32 && lane >= cc_) remv |= (acc | acco);                               \
    kept_cnt += (int)__popcll(kept);                                                  \
} while (0)

__global__ __launch_bounds__(64, 1) void k_nms(const u64* __restrict__ valid,
                                               const u64* __restrict__ sup,
                                               const u64* __restrict__ diagd,
                                               const float4* __restrict__ boxes,
                                               float4* __restrict__ out) {
    int b = blockIdx.x;
    int lane = threadIdx.x;             // 64
    int w = lane & 31, hh = lane >> 5;
    const u64* S = sup + (size_t)b * RANKP * NWORD;
    const u64* Dv = diagd + (size_t)b * (NWORD * 64);
    uint32_t voff  = (uint32_t)(hh * 8192 + w * 8);   // rows hh*32..hh*32+15 via imm
    uint32_t vdiag = (uint32_t)(lane * 8);
    u64 remv = (lane < 32) ? ~valid[(size_t)b * NWORD + lane] : 0ull;
    QLIST(DECLA) u64 Ad;
    QLIST(DECLB) u64 Bd;
    int kept_cnt = 0;
    ISSUE_ROWS(A, 0);
    WAITV0();
    for (int c = 0; c < NWORD; c += 2) {
        ISSUE_ROWS(B, c + 1);
        NMS_BODY(ACCA, Ad, c);
        if (kept_cnt >= POST) goto done;
        WAITV0();
        ISSUE_ROWS(A, c + 2);
        NMS_BODY(ACCB, Bd, c + 1);
        if (kept_cnt >= POST) goto done;
        WAITV0();
    }
done: ;
    // ---- epilogue: stable partition (kept first) -> top-1000 gather ----
    int tot = 0;
    for (int ww = 0; ww < NWORD; ++ww)
        tot += (int)__popcll(~readlane_u64(remv, ww));
    u64 below = (1ull << lane) - 1ull;
    int kcum = 0, ucum = 0;
    for (int ww = 0; ww < NWORD; ++ww) {
        u64 kw = ~readlane_u64(remv, ww);
        int pc = (int)__popcll(kw);
        bool kp = (kw >> lane) & 1ull;
        int pos;
        if (kp) pos = kcum + (int)__popcll(kw & below);
        else    pos = tot + ucum + (int)__popcll((~kw) & below);
        if (pos < POST) out[(size_t)b * POST + pos] = boxes[(size_t)b * RANKP + ww * 64 + lane];
        kcum += pc;
        ucum += 64 - pc;
    }
}

extern "C" void kernel_launch(void* const* d_in, const int* in_sizes, int n_in,
                              void* d_out, int out_size, void* d_ws, size_t ws_size,
                              hipStream_t stream) {
    const float* anchors = (const float*)d_in[0];   // [N,4]
    const float* obj     = (const float*)d_in[1];   // [B,N]
    const float* deltas  = (const float*)d_in[2];   // [B,N,4]
    char* ws = (char*)d_ws;

    uint32_t* hist   = (uint32_t*)(ws + 0);        // 131072
    uint32_t* cnt    = (uint32_t*)(ws + 131072);   // 256
    u64*      cand   = (u64*)(ws + 131584);        // B*4096*8 = 262144 -> 393728
    float4*   boxes  = (float4*)(ws + 393728);     // B*2048*16 = 524288 -> 918016
    u64*      valid  = (u64*)(ws + 918016);        // 2048 -> 920064
    u64*      sup    = (u64*)(ws + 920064);        // B*2048*32*8 = 4194304 -> 5114368
    u64*      diagd  = (u64*)(ws + 5114368);       // B*32*64*8 = 131072 -> 5245440

    hipMemsetAsync(ws, 0, 131328, stream);  // hist + cnt

    dim3 gscan(SCAN_BLOCKS, B);
    k_hist<<<gscan, 256, 0, stream>>>((const float4*)obj, hist);
    k_compact<<<gscan, 256, 0, stream>>>((const float4*)obj, hist, cnt, cand);
    dim3 grank(B, CAP / 64);
    k_rankdec<<<grank, 64, 0, stream>>>(cnt, cand, (const float4*)anchors,
                                        (const float4*)deltas, boxes);
    dim3 gmask(B, NTRI);
    k_mask<<<gmask, 64, 0, stream>>>(boxes, sup, diagd, valid);
    k_nms<<<B, 64, 0, stream>>>(valid, sup, diagd, boxes, (float4*)d_out);
}

// Round 14
// 107.883 us; speedup vs baseline: 1.3608x; 1.0246x over previous
//
#include <hip/hip_runtime.h>
#include <stdint.h>

#define B 8
#define N 460800
#define NV4 115200          // N/4 float4 scores per image
#define PRE 2000
#define POST 1000
#define CAP 4096
#define NBIN 4096
#define RANKP 2048
#define NWORD 32
#define NMS_T 0.7f
#define XCLIP 4.135166556742356

#define SCAN_BLOCKS 45      // 45*256*10 = 115200
#define SCAN_ITER 10
#define SCAN_STRIDE (SCAN_BLOCKS * 256)

typedef unsigned long long u64;

__device__ __forceinline__ uint32_t fkey(float f) {
    uint32_t u = __float_as_uint(f);
    return (u & 0x80000000u) ? ~u : (u | 0x80000000u);
}

__device__ __forceinline__ u64 readlane_u64(u64 v, int lane) {
    uint32_t lo = __builtin_amdgcn_readlane((uint32_t)v, lane);
    uint32_t hi = __builtin_amdgcn_readlane((uint32_t)(v >> 32), lane);
    return ((u64)hi << 32) | lo;
}

// ---------------- Stage 1: per-image histogram of score keys (top 12 bits) ----------------
__global__ __launch_bounds__(256) void k_hist(const float4* __restrict__ obj4,
                                              uint32_t* __restrict__ hist) {
    __shared__ uint32_t lh[2][NBIN];   // 32 KiB, 2-way replicated to cut contention
    int b = blockIdx.y;
    for (int i = threadIdx.x; i < NBIN; i += 256) { lh[0][i] = 0; lh[1][i] = 0; }
    __syncthreads();
    const float4* s = obj4 + (size_t)b * NV4;
    int t0 = blockIdx.x * 256 + threadIdx.x;
    uint32_t* h = lh[threadIdx.x & 1];
    float4 v[SCAN_ITER];
#pragma unroll
    for (int k = 0; k < SCAN_ITER; ++k) v[k] = s[t0 + k * SCAN_STRIDE];
#pragma unroll
    for (int k = 0; k < SCAN_ITER; ++k) {
        atomicAdd(&h[fkey(v[k].x) >> 20], 1u);
        atomicAdd(&h[fkey(v[k].y) >> 20], 1u);
        atomicAdd(&h[fkey(v[k].z) >> 20], 1u);
        atomicAdd(&h[fkey(v[k].w) >> 20], 1u);
    }
    __syncthreads();
    uint32_t* gh = hist + (size_t)b * NBIN;
    for (int i = threadIdx.x; i < NBIN; i += 256) {
        uint32_t s2 = lh[0][i] + lh[1][i];
        if (s2) atomicAdd(&gh[i], s2);
    }
}

// ---------------- Stage 2+3 fused: wave 0 computes cutoff bin, then compact ------------
#define LBUF 2048
__global__ __launch_bounds__(256) void k_compact(const float4* __restrict__ obj4,
                                                 const uint32_t* __restrict__ hist,
                                                 uint32_t* __restrict__ cnt,
                                                 u64* __restrict__ cand) {
    __shared__ u64 buf[LBUF];          // 16 KiB
    __shared__ uint32_t lcnt, base, cutsh;
    int b = blockIdx.y;
    if (threadIdx.x == 0) lcnt = 0;
    if (threadIdx.x < 64) {
        int lane = threadIdx.x;
        const uint32_t* h = hist + (size_t)b * NBIN;
        uint32_t gs = 0;
        for (int t = 0; t < 64; ++t) gs += h[lane * 64 + t];
        uint32_t suf = gs;
        for (int d = 1; d < 64; d <<= 1) {
            uint32_t vv = __shfl_down(suf, d);
            if (lane + d < 64) suf += vv;
        }
        unsigned long long m = __ballot(suf >= PRE);
        int G = 63 - __clzll(m);
        uint32_t A = 0;
        if (G < 63) A = __shfl(suf, G + 1);
        uint32_t hv = h[G * 64 + lane];
        uint32_t suf2 = hv;
        for (int d = 1; d < 64; d <<= 1) {
            uint32_t vv = __shfl_down(suf2, d);
            if (lane + d < 64) suf2 += vv;
        }
        unsigned long long m2 = __ballot(A + suf2 >= PRE);
        int t2 = 63 - __clzll(m2);
        if (lane == 0) cutsh = (uint32_t)(G * 64 + t2);
    }
    __syncthreads();
    uint32_t cb = cutsh;
    const float4* s = obj4 + (size_t)b * NV4;
    int t0 = blockIdx.x * 256 + threadIdx.x;
    float4 v[SCAN_ITER];
#pragma unroll
    for (int k = 0; k < SCAN_ITER; ++k) v[k] = s[t0 + k * SCAN_STRIDE];
#pragma unroll
    for (int k = 0; k < SCAN_ITER; ++k) {
        int i4 = (t0 + k * SCAN_STRIDE) * 4;
        float fv[4] = {v[k].x, v[k].y, v[k].z, v[k].w};
#pragma unroll
        for (int c = 0; c < 4; ++c) {
            uint32_t key = fkey(fv[c]);
            if ((key >> 20) >= cb) {
                uint32_t p = atomicAdd(&lcnt, 1u);
                u64 e = ((u64)key << 32) | (uint32_t)(~(uint32_t)(i4 + c));
                if (p < LBUF) buf[p] = e;
                else {
                    uint32_t g = atomicAdd(&cnt[b], 1u);
                    if (g < CAP) cand[(size_t)b * CAP + g] = e;
                }
            }
        }
    }
    __syncthreads();
    uint32_t nb = lcnt < LBUF ? lcnt : LBUF;
    if (threadIdx.x == 0) base = atomicAdd(&cnt[b], nb);
    __syncthreads();
    uint32_t bs = base;
    for (uint32_t t = threadIdx.x; t < nb; t += 256) {
        uint32_t g = bs + t;
        if (g < CAP) cand[(size_t)b * CAP + g] = buf[t];
    }
}

// ---------------- Stage 4+5: counting-rank (readlane broadcast) + decode ----------------
// rank_i = #{j : key_j > key_i} (keys unique via idx tie-break). One wave per 64 slots;
// j-stream loaded coalesced per-lane with a 3-deep NAMED-REGISTER prefetch rotation
// (never arrays — allocator demotes those), broadcast via v_readlane; two independent
// accumulators break the VCC serialization. No SMEM/LDS anywhere in the chain.
__global__ __launch_bounds__(64) void k_rankdec(const uint32_t* __restrict__ cnt,
                                                const u64* __restrict__ cand,
                                                const float4* __restrict__ anchors,
                                                const float4* __restrict__ deltas,
                                                float4* __restrict__ boxes) {
    int b = blockIdx.x;
    int lane = threadIdx.x;                       // 64
    int slot = blockIdx.y * 64 + lane;            // 0..4095
    uint32_t n = cnt[b]; if (n > CAP) n = CAP;
    const u64* C = cand + (size_t)b * CAP;
    u64 mykey = (slot < (int)n) ? C[slot] : 0ull;
    int ng = ((int)n + 63) >> 6;
    // guarded group load: address clamped in-bounds, value masked by j<n
    auto ld = [&](int g) -> u64 {
        int j = g * 64 + lane;
        int jc = j < (CAP - 1) ? j : (CAP - 1);
        u64 kv = C[jc];
        return (j < (int)n) ? kv : 0ull;          // 0 never counts (real keys have MSB set)
    };
    u64 kv0 = ld(0), kv1 = ld(1), kv2 = ld(2);
    int r0 = 0, r1 = 0;
    for (int g = 0; g < ng; ++g) {
        u64 kvn = ld(g + 3);
#pragma unroll
        for (int t = 0; t < 64; t += 2) {
            u64 ka = readlane_u64(kv0, t);
            u64 kb = readlane_u64(kv0, t + 1);
            r0 += (ka > mykey) ? 1 : 0;
            r1 += (kb > mykey) ? 1 : 0;
        }
        kv0 = kv1; kv1 = kv2; kv2 = kvn;
    }
    int r = r0 + r1;
    int rank = (slot < (int)n) ? r : slot;        // pads cover rows [n,2048) bijectively
    if (rank < RANKP) {
        float4 outb = make_float4(0.f, 0.f, 0.f, 0.f);
        if (slot < (int)n && rank < PRE) {
            uint32_t idx = ~(uint32_t)mykey;
            if (idx < N) {
                float4 a = anchors[idx];
                float4 d = deltas[(size_t)b * N + idx];
                float w = a.z - a.x, h = a.w - a.y;
                float cx = a.x + 0.5f * w, cy = a.y + 0.5f * h;
                float dw = fminf(d.z, (float)XCLIP);
                float dh = fminf(d.w, (float)XCLIP);
                float pcx = d.x * w + cx, pcy = d.y * h + cy;
                float pw = expf(dw) * w, ph = expf(dh) * h;
                float x1 = pcx - 0.5f * pw, y1 = pcy - 0.5f * ph;
                float x2 = pcx + 0.5f * pw, y2 = pcy + 0.5f * ph;
                x1 = fminf(fmaxf(x1, 0.f), 1024.f);
                y1 = fminf(fmaxf(y1, 0.f), 1024.f);
                x2 = fminf(fmaxf(x2, 0.f), 1024.f);
                y2 = fminf(fmaxf(y2, 0.f), 1024.f);
                outb = make_float4(x1, y1, x2, y2);
            }
        }
        boxes[(size_t)b * RANKP + rank] = outb;
    }
}

// ---------------- Stage 6a: pairwise suppression bitmask + diag + valid ----------------
#define NTRI (NWORD * (NWORD + 1) / 2)   // 528
__global__ void k_mask(const float4* __restrict__ boxes, u64* __restrict__ sup,
                       u64* __restrict__ diagd, u64* __restrict__ valid) {
    int b = blockIdx.x;
    int L = blockIdx.y;
    int ti = 0, rem = L;
    while (rem >= NWORD - ti) { rem -= NWORD - ti; ++ti; }
    int tj = ti + rem;
    __shared__ float4 jb[64];
    __shared__ float ja[64];
    int t = threadIdx.x;  // 64 threads
    const float4* bx = boxes + (size_t)b * RANKP;
    float4 v = bx[tj * 64 + t];
    jb[t] = v;
    ja[t] = (v.z - v.x) * (v.w - v.y);
    int i = ti * 64 + t;
    float4 bi = bx[i];
    float ai = (bi.z - bi.x) * (bi.w - bi.y);
    __syncthreads();
    u64 word = 0;
    for (int jj = 0; jj < 64; ++jj) {
        int j = tj * 64 + jj;
        float4 bj = jb[jj];
        float xx1 = fmaxf(bi.x, bj.x), yy1 = fmaxf(bi.y, bj.y);
        float xx2 = fminf(bi.z, bj.z), yy2 = fminf(bi.w, bj.w);
        float iw = fmaxf(xx2 - xx1, 0.f), ih = fmaxf(yy2 - yy1, 0.f);
        float inter = iw * ih;
        float iou = inter / (ai + ja[jj] - inter);
        if (j > i && iou > NMS_T) word |= 1ull << jj;
    }
    sup[((size_t)b * RANKP + i) * NWORD + tj] = word;
    if (ti == tj) {
        diagd[((size_t)b * NWORD + ti) * 64 + t] = word;
        bool ok = !((bi.z - bi.x < 1e-3f) || (bi.w - bi.y < 1e-3f));
        u64 bal = __ballot(ok);
        if (t == 0) valid[(size_t)b * NWORD + ti] = bal;
    }
}

// ---------------- Stage 6b+7: chunked greedy NMS, pure-register asm pipeline ----------------
// NO LDS, NO SMEM: rows (32 u64) + diag word per chunk live in named registers, loaded
// by inline-asm global_load_dwordx2 (A/B double buffer). Unroll-2 loop: issue next batch
// -> sched_barrier(0) -> compute current -> vmcnt(0)+sched_barrier.
// CRITICAL (r13 post-mortem): the sched_barrier(0) AFTER each ISSUE_ROWS prevents LLVM
// from hoisting the (register-only) compute above the issue; without it the compiler
// proves A dead before B's write, coalesces A/B into one register set (VGPR=72), and
// the double-buffer silently degenerates to a serial wait-compute-issue loop.
// sup lower-triangle words (w < row's chunk) are NEVER written (0xAA poison from the
// harness) — the `lane >= c` guard keeps them out of remv. Do not remove it.
#define QLIST(X) X(0) X(1) X(2) X(3) X(4) X(5) X(6) X(7) X(8) X(9) X(10) X(11) \
    X(12) X(13) X(14) X(15) X(16) X(17) X(18) X(19) X(20) X(21) X(22) X(23)    \
    X(24) X(25) X(26) X(27) X(28) X(29) X(30) X(31)

#define DECLA(i) u64 A##i;
#define DECLB(i) u64 B##i;
#define ACCA(i) { u64 m_ = (u64)(int64_t)((int32_t)(kk << (31 - i)) >> 31); acc |= A##i & m_; }
#define ACCB(i) { u64 m_ = (u64)(int64_t)((int32_t)(kk << (31 - i)) >> 31); acc |= B##i & m_; }

#define ISSUE_ROWS(P, CC) do {                                                        \
    const char* g1_ = (const char*)S + ((size_t)((CC) & (NWORD - 1)) << 14);          \
    const char* g2_ = g1_ + 4096;                                                     \
    const char* gd_ = (const char*)Dv + ((size_t)((CC) & (NWORD - 1)) << 9);          \
    asm volatile(                                                                     \
        "global_load_dwordx2 %[q0], %[vo], %[sp] offset:0\n\t"                        \
        "global_load_dwordx2 %[q1], %[vo], %[sp] offset:256\n\t"                      \
        "global_load_dwordx2 %[q2], %[vo], %[sp] offset:512\n\t"                      \
        "global_load_dwordx2 %[q3], %[vo], %[sp] offset:768\n\t"                      \
        "global_load_dwordx2 %[q4], %[vo], %[sp] offset:1024\n\t"                     \
        "global_load_dwordx2 %[q5], %[vo], %[sp] offset:1280\n\t"                     \
        "global_load_dwordx2 %[q6], %[vo], %[sp] offset:1536\n\t"                     \
        "global_load_dwordx2 %[q7], %[vo], %[sp] offset:1792\n\t"                     \
        "global_load_dwordx2 %[q8], %[vo], %[sp] offset:2048\n\t"                     \
        "global_load_dwordx2 %[q9], %[vo], %[sp] offset:2304\n\t"                     \
        "global_load_dwordx2 %[q10], %[vo], %[sp] offset:2560\n\t"                    \
        "global_load_dwordx2 %[q11], %[vo], %[sp] offset:2816\n\t"                    \
        "global_load_dwordx2 %[q12], %[vo], %[sp] offset:3072\n\t"                    \
        "global_load_dwordx2 %[q13], %[vo], %[sp] offset:3328\n\t"                    \
        "global_load_dwordx2 %[q14], %[vo], %[sp] offset:3584\n\t"                    \
        "global_load_dwordx2 %[q15], %[vo], %[sp] offset:3840\n\t"                    \
        : [q0]"=&v"(P##0), [q1]"=&v"(P##1), [q2]"=&v"(P##2), [q3]"=&v"(P##3),         \
          [q4]"=&v"(P##4), [q5]"=&v"(P##5), [q6]"=&v"(P##6), [q7]"=&v"(P##7),         \
          [q8]"=&v"(P##8), [q9]"=&v"(P##9), [q10]"=&v"(P##10), [q11]"=&v"(P##11),     \
          [q12]"=&v"(P##12), [q13]"=&v"(P##13), [q14]"=&v"(P##14), [q15]"=&v"(P##15)  \
        : [vo]"v"(voff), [sp]"s"(g1_));                                               \
    asm volatile(                                                                     \
        "global_load_dwordx2 %[q16], %[vo], %[sp] offset:0\n\t"                       \
        "global_load_dwordx2 %[q17], %[vo], %[sp] offset:256\n\t"                     \
        "global_load_dwordx2 %[q18], %[vo], %[sp] offset:512\n\t"                     \
        "global_load_dwordx2 %[q19], %[vo], %[sp] offset:768\n\t"                     \
        "global_load_dwordx2 %[q20], %[vo], %[sp] offset:1024\n\t"                    \
        "global_load_dwordx2 %[q21], %[vo], %[sp] offset:1280\n\t"                    \
        "global_load_dwordx2 %[q22], %[vo], %[sp] offset:1536\n\t"                    \
        "global_load_dwordx2 %[q23], %[vo], %[sp] offset:1792\n\t"                    \
        "global_load_dwordx2 %[q24], %[vo], %[sp] offset:2048\n\t"                    \
        "global_load_dwordx2 %[q25], %[vo], %[sp] offset:2304\n\t"                    \
        "global_load_dwordx2 %[q26], %[vo], %[sp] offset:2560\n\t"                    \
        "global_load_dwordx2 %[q27], %[vo], %[sp] offset:2816\n\t"                    \
        "global_load_dwordx2 %[q28], %[vo], %[sp] offset:3072\n\t"                    \
        "global_load_dwordx2 %[q29], %[vo], %[sp] offset:3328\n\t"                    \
        "global_load_dwordx2 %[q30], %[vo], %[sp] offset:3584\n\t"                    \
        "global_load_dwordx2 %[q31], %[vo], %[sp] offset:3840\n\t"                    \
        "global_load_dwordx2 %[qd], %[vd], %[sd] offset:0\n\t"                        \
        : [q16]"=&v"(P##16), [q17]"=&v"(P##17), [q18]"=&v"(P##18), [q19]"=&v"(P##19), \
          [q20]"=&v"(P##20), [q21]"=&v"(P##21), [q22]"=&v"(P##22), [q23]"=&v"(P##23), \
          [q24]"=&v"(P##24), [q25]"=&v"(P##25), [q26]"=&v"(P##26), [q27]"=&v"(P##27), \
          [q28]"=&v"(P##28), [q29]"=&v"(P##29), [q30]"=&v"(P##30), [q31]"=&v"(P##31), \
          [qd]"=&v"(P##d)                                                             \
        : [vo]"v"(voff), [sp]"s"(g2_), [vd]"v"(vdiag), [sd]"s"(gd_));                 \
    __builtin_amdgcn_sched_barrier(0);  /* pin: compute must NOT hoist above issue */ \
} while (0)

#define WAITV0() do { asm volatile("s_waitcnt vmcnt(0)" ::: "memory");                \
                      __builtin_amdgcn_sched_barrier(0); } while (0)

#define NMS_BODY(ACCM, DREG, CC) do {                                                 \
    int cc_ = (CC);                                                                   \
    u64 dcur_ = (DREG);                                                               \
    u64 scur = readlane_u64(remv, cc_);                                               \
    _Pragma("unroll") for (int g = 0; g < 4; ++g) {                                   \
        u64 dd[16];                                                                   \
        _Pragma("unroll") for (int i = 0; i < 16; ++i)                                \
            dd[i] = readlane_u64(dcur_, g * 16 + i);                                  \
        _Pragma("unroll") for (int i = 0; i < 16; ++i) {                              \
            int row = g * 16 + i;                                                     \
            if (!((scur >> row) & 1ull)) scur |= dd[i];                               \
        }                                                                             \
    }                                                                                 \
    u64 kept = ~scur;                                                                 \
    uint32_t kk = hh ? (uint32_t)(kept >> 32) : (uint32_t)kept;                       \
    u64 acc = 0;                                                                      \
    QLIST(ACCM)                                                                       \
    u64 acco = __shfl(acc, lane + 32);                                                \
    if (lane < 32 && lane >= cc_) remv |= (acc | acco);                               \
    kept_cnt += (int)__popcll(kept);                                                  \
} while (0)

__global__ __launch_bounds__(64, 1) void k_nms(const u64* __restrict__ valid,
                                               const u64* __restrict__ sup,
                                               const u64* __restrict__ diagd,
                                               const float4* __restrict__ boxes,
                                               float4* __restrict__ out) {
    int b = blockIdx.x;
    int lane = threadIdx.x;             // 64
    int w = lane & 31, hh = lane >> 5;
    const u64* S = sup + (size_t)b * RANKP * NWORD;
    const u64* Dv = diagd + (size_t)b * (NWORD * 64);
    uint32_t voff  = (uint32_t)(hh * 8192 + w * 8);   // rows hh*32..hh*32+15 via imm
    uint32_t vdiag = (uint32_t)(lane * 8);
    u64 remv = (lane < 32) ? ~valid[(size_t)b * NWORD + lane] : 0ull;
    QLIST(DECLA) u64 Ad;
    QLIST(DECLB) u64 Bd;
    int kept_cnt = 0;
    ISSUE_ROWS(A, 0);
    WAITV0();
    for (int c = 0; c < NWORD; c += 2) {
        ISSUE_ROWS(B, c + 1);
        NMS_BODY(ACCA, Ad, c);
        if (kept_cnt >= POST) goto done;
        WAITV0();
        ISSUE_ROWS(A, c + 2);
        NMS_BODY(ACCB, Bd, c + 1);
        if (kept_cnt >= POST) goto done;
        WAITV0();
    }
done: ;
    // ---- epilogue: stable partition (kept first) -> top-1000 gather ----
    int tot = 0;
    for (int ww = 0; ww < NWORD; ++ww)
        tot += (int)__popcll(~readlane_u64(remv, ww));
    u64 below = (1ull << lane) - 1ull;
    int kcum = 0, ucum = 0;
    for (int ww = 0; ww < NWORD; ++ww) {
        u64 kw = ~readlane_u64(remv, ww);
        int pc = (int)__popcll(kw);
        bool kp = (kw >> lane) & 1ull;
        int pos;
        if (kp) pos = kcum + (int)__popcll(kw & below);
        else    pos = tot + ucum + (int)__popcll((~kw) & below);
        if (pos < POST) out[(size_t)b * POST + pos] = boxes[(size_t)b * RANKP + ww * 64 + lane];
        kcum += pc;
        ucum += 64 - pc;
    }
}

extern "C" void kernel_launch(void* const* d_in, const int* in_sizes, int n_in,
                              void* d_out, int out_size, void* d_ws, size_t ws_size,
                              hipStream_t stream) {
    const float* anchors = (const float*)d_in[0];   // [N,4]
    const float* obj     = (const float*)d_in[1];   // [B,N]
    const float* deltas  = (const float*)d_in[2];   // [B,N,4]
    char* ws = (char*)d_ws;

    uint32_t* hist   = (uint32_t*)(ws + 0);        // 131072
    uint32_t* cnt    = (uint32_t*)(ws + 131072);   // 256
    u64*      cand   = (u64*)(ws + 131584);        // B*4096*8 = 262144 -> 393728
    float4*   boxes  = (float4*)(ws + 393728);     // B*2048*16 = 524288 -> 918016
    u64*      valid  = (u64*)(ws + 918016);        // 2048 -> 920064
    u64*      sup    = (u64*)(ws + 920064);        // B*2048*32*8 = 4194304 -> 5114368
    u64*      diagd  = (u64*)(ws + 5114368);       // B*32*64*8 = 131072 -> 5245440

    hipMemsetAsync(ws, 0, 131328, stream);  // hist + cnt

    dim3 gscan(SCAN_BLOCKS, B);
    k_hist<<<gscan, 256, 0, stream>>>((const float4*)obj, hist);
    k_compact<<<gscan, 256, 0, stream>>>((const float4*)obj, hist, cnt, cand);
    dim3 grank(B, CAP / 64);
    k_rankdec<<<grank, 64, 0, stream>>>(cnt, cand, (const float4*)anchors,
                                        (const float4*)deltas, boxes);
    dim3 gmask(B, NTRI);
    k_mask<<<gmask, 64, 0, stream>>>(boxes, sup, diagd, valid);
    k_nms<<<B, 64, 0, stream>>>(valid, sup, diagd, boxes, (float4*)d_out);
}